// Round 15
// baseline (8726.176 us; speedup 1.0000x reference)
//
#include <hip/hip_runtime.h>
#include <stdint.h>

#define TT 512

typedef __fp16   f16x8  __attribute__((ext_vector_type(8)));
typedef float    f32x4  __attribute__((ext_vector_type(4)));
typedef __fp16   fp16x2 __attribute__((ext_vector_type(2)));
typedef uint32_t u32x2  __attribute__((ext_vector_type(2)));

__device__ __forceinline__ f32x4 mfma16(f16x8 a, f16x8 b, f32x4 c) {
    return __builtin_amdgcn_mfma_f32_16x16x32_f16(a, b, c, 0, 0, 0);
}
__device__ __forceinline__ uint32_t pkf16(float a, float b) {
    fp16x2 h = __builtin_amdgcn_cvt_pkrtz(a, b);
    return __builtin_bit_cast(uint32_t, h);
}

#define REP4(M) M(0)M(1)M(2)M(3)
#define REP8(M) M(0)M(1)M(2)M(3)M(4)M(5)M(6)M(7)

// A-operand gather with per-column scale SC (weights transposed, z^T form):
#define GA(SRC, T, F, SC) (f16x8){ \
  (__fp16)((SRC)[(32*(F)+8*quad+0)*256 + 16*(T)+l15] * (SC)), \
  (__fp16)((SRC)[(32*(F)+8*quad+1)*256 + 16*(T)+l15] * (SC)), \
  (__fp16)((SRC)[(32*(F)+8*quad+2)*256 + 16*(T)+l15] * (SC)), \
  (__fp16)((SRC)[(32*(F)+8*quad+3)*256 + 16*(T)+l15] * (SC)), \
  (__fp16)((SRC)[(32*(F)+8*quad+4)*256 + 16*(T)+l15] * (SC)), \
  (__fp16)((SRC)[(32*(F)+8*quad+5)*256 + 16*(T)+l15] * (SC)), \
  (__fp16)((SRC)[(32*(F)+8*quad+6)*256 + 16*(T)+l15] * (SC)), \
  (__fp16)((SRC)[(32*(F)+8*quad+7)*256 + 16*(T)+l15] * (SC)) }

// ============================================================================
// R25 LAYER-PARALLEL kernel: 128 blocks = 4 layers x 32 row-groups (32 rows).
// Per block: 8 waves = 2 x 16-row groups (rgl) x 4 unit-quarter waves (w).
// Wave (rgl,w): units 16w..16w+15, all 4 gates (tiles {w,4+w,8+w,12+w}),
// 8 W + 8 U MFMA/step -- per-SIMD matrix load 4x lower than the 64-block
// design, and SIMD-mates are INDEPENDENT recurrences (different row-groups).
// Inter-layer h: global ring in d_ws [lp][rg][rgl][slot8][16 rows][64 u] f16,
// relaxed agent-scope counters + acquire/release fences (XCD-safe, G16).
// Intra-layer siblings: LDS ring + wg-scope flags (R14 protocol).
// Per-unit math / gates / epilogue = R22's VERIFIED path (absmax 2.384186e-07).
// ============================================================================
#define DECL4(j) f16x8 uA##j##_0, uA##j##_1, wA##j##_0, wA##j##_1; f32x4 bias##j;
#define LOAD4(j) { \
  const int Tg_ = 4*(j) + w; \
  const float sc_ = ((j) == 2) ? 1.0f : -1.4426950408889634f; \
  uA##j##_0 = GA(Uw, Tg_, 0, sc_); uA##j##_1 = GA(Uw, Tg_, 1, sc_); \
  bias##j = (f32x4){ bw_[16*Tg_ + 4*quad + 0] * sc_, bw_[16*Tg_ + 4*quad + 1] * sc_, \
                     bw_[16*Tg_ + 4*quad + 2] * sc_, bw_[16*Tg_ + 4*quad + 3] * sc_ }; \
  if (l > 0) { wA##j##_0 = GA(Wsrc, Tg_, 0, sc_); wA##j##_1 = GA(Wsrc, Tg_, 1, sc_); } \
  else { wA##j##_0 = __builtin_bit_cast(f16x8, (f32x4){ \
           Wx0[16*Tg_+4*quad+0] * sc_, Wx0[16*Tg_+4*quad+1] * sc_, \
           Wx0[16*Tg_+4*quad+2] * sc_, Wx0[16*Tg_+4*quad+3] * sc_ }); \
         wA##j##_1 = wA##j##_0; } }

#define MW0_(j) acc##j = mfma16(wA##j##_0, xBp0, bias##j);
#define MW1_(j) acc##j = mfma16(wA##j##_1, xBp1, acc##j);
#define MX_(j)  acc##j = bias##j + __builtin_bit_cast(f32x4, wA##j##_0) * xvp4;
#define MU0_(j) acc##j = mfma16(uA##j##_0, hB0, acc##j);
#define MU1_(j) acc##j = mfma16(uA##j##_1, hB1, acc##j);

#define MFMA_SEG4(t_) { \
  const __fp16* hp_ = hb_rgl + (((t_)-1)&7)*1152 + l15*72 + 8*quad; \
  f16x8 hB0 = *(const f16x8*)hp_; \
  f16x8 hB1 = *(const f16x8*)(hp_ + 32); \
  if (l > 0) { REP4(MW0_) REP4(MW1_) } \
  else       { f32x4 xvp4 = {xvp, xvp, xvp, xvp}; REP4(MX_) } \
  REP4(MU0_) \
  REP4(MU1_) }

#define GATE_SEG4(tg_, SV_) { \
  f32x4 ei_, ef_, eo_; \
  _Pragma("unroll") for (int r_ = 0; r_ < 4; ++r_) { \
    ei_[r_] = __builtin_amdgcn_exp2f(acc0[r_]); \
    ef_[r_] = __builtin_amdgcn_exp2f(acc1[r_]); \
    eo_[r_] = __builtin_amdgcn_exp2f(acc3[r_]); \
  } \
  f32x4 si_, sf_, so_; \
  _Pragma("unroll") for (int r_ = 0; r_ < 4; ++r_) { \
    si_[r_] = __builtin_amdgcn_rcpf(1.0f + ei_[r_]); \
    sf_[r_] = __builtin_amdgcn_rcpf(1.0f + ef_[r_]); \
    so_[r_] = __builtin_amdgcn_rcpf(1.0f + eo_[r_]); \
  } \
  const f32x4 z4_ = {0.f, 0.f, 0.f, 0.f}; \
  f32x4 rg_ = __builtin_elementwise_max(acc2, z4_); \
  f32x4 cv_ = sf_ * cst0 + si_ * rg_; \
  cst0 = cv_; \
  f32x4 hv_ = so_ * __builtin_elementwise_max(cv_, z4_); \
  u32x2 pv_ = { pkf16(hv_[0], hv_[1]), pkf16(hv_[2], hv_[3]) }; \
  *(u32x2*)(hb_rgl + ((tg_)&7)*1152 + l15*72 + 16*w + 4*quad) = pv_; \
  if (l < 3) *(u32x2*)(rout + ((tg_)&7)*1024 + l15*64 + 16*w + 4*quad) = pv_; \
  if (SV_) hK0 = hv_; }

// LDS sibling wait (wg scope, cheap)
#define LWAIT(cache, idx, need) \
  while ((cache) < (need)) \
    (cache) = __hip_atomic_load(&Pf[idx], __ATOMIC_ACQUIRE, __HIP_MEMORY_SCOPE_WORKGROUP);
// Global 4-counter wait: relaxed polls (no L2 inv per poll), one acquire fence
// only when a NEW satisfying value is observed.
#define PGL(i) __hip_atomic_load(&Pg[i], __ATOMIC_RELAXED, __HIP_MEMORY_SCOPE_AGENT)
#define GWAIT4(c0, c1, c2, c3, base, need) \
  if ((c0) < (need) || (c1) < (need) || (c2) < (need) || (c3) < (need)) { \
    do { c0 = PGL((base)+0); c1 = PGL((base)+1); c2 = PGL((base)+2); c3 = PGL((base)+3); } \
    while ((c0) < (need) || (c1) < (need) || (c2) < (need) || (c3) < (need)); \
    __builtin_amdgcn_fence(__ATOMIC_ACQUIRE, "agent"); \
  }

__global__ __launch_bounds__(512)
__attribute__((amdgpu_waves_per_eu(2, 2)))
void lstm_lp(
    const float* __restrict__ x,
    const float* __restrict__ Wx0, const float* __restrict__ U0, const float* __restrict__ b0,
    const float* __restrict__ Wx1, const float* __restrict__ U1, const float* __restrict__ b1,
    const float* __restrict__ Wx2, const float* __restrict__ U2, const float* __restrict__ b2,
    const float* __restrict__ Wx3, const float* __restrict__ U3, const float* __restrict__ b3,
    const float* __restrict__ Wd,  const float* __restrict__ bd,
    float* __restrict__ out, void* __restrict__ ws)
{
    // dwords: hb f16 [0,9216) | xs f32 [9216,26112) | red [26112,26176) | Pf [26176,26184)
    extern __shared__ uint32_t smem[];
    __fp16* hb16 = (__fp16*)smem;              // [rgl 2][slot8][row16][unit64 pad72]
    float*  xs   = (float*)(smem + 9216);      // [t 512][33] (l==0); scratch for l==3 epilogue
    float*  red  = (float*)(smem + 26112);     // [rgl 2][2][16]
    int*    Pf   = (int*)(smem + 26176);       // [rgl 2][w 4] sibling progress

    __fp16* ring = (__fp16*)ws;                          // 192 segs x 8 slots x 1024 f16
    int*    Pg   = (int*)((char*)ws + 3145728);          // 1024 ints

    const int tid  = threadIdx.x;
    const int lane = tid & 63;
    const int l15  = lane & 15;
    const int quad = lane >> 4;
    const int wv   = tid >> 6;
    const int rgl  = wv >> 2;                  // 16-row group within block
    const int w    = wv & 3;                   // unit-quarter
    const int l    = blockIdx.x >> 5;          // layer
    const int rg   = blockIdx.x & 31;          // row-group (32 rows)

    // ---- staging ----
    for (int i = tid; i < 26184; i += 512) smem[i] = 0;
    __syncthreads();
    if (l == 0) {
        for (int i = tid; i < 32 * TT; i += 512) {
            int row = i >> 9, t_ = i & (TT - 1);
            xs[t_ * 33 + row] = x[(rg * 32 + row) * TT + t_];
        }
    }

    const float* Uw   = (l == 0) ? U0 : (l == 1) ? U1 : (l == 2) ? U2 : U3;
    const float* bw_  = (l == 0) ? b0 : (l == 1) ? b1 : (l == 2) ? b2 : b3;
    const float* Wsrc = (l == 1) ? Wx1 : (l == 2) ? Wx2 : (l == 3) ? Wx3 : U0;

    REP4(DECL4)
    REP4(LOAD4)

    f32x4 acc0, acc1, acc2, acc3;
    f32x4 cst0 = {0,0,0,0};
    f32x4 hK0  = {0,0,0,0};

    __fp16* hb_rgl = hb16 + rgl * 9216;        // own 16-row LDS ring
    const __fp16* rin = ring + (size_t)(((l - 1) * 32 + rg) * 2 + rgl) * 8192; // l>0
    __fp16*       rout = (__fp16*)ring + (size_t)((l * 32 + rg) * 2 + rgl) * 8192; // l<3
    const int uBase = (((l - 1) * 32 + rg) * 2 + rgl) * 4;  // upstream flags (l>0)
    const int dBase = (((l + 1) * 32 + rg) * 2 + rgl) * 4;  // downstream flags (l<3)
    const int own   = ((l * 32 + rg) * 2 + rgl) * 4 + w;

    f16x8 xBp0 = {}, xBp1 = {};
    float xvp = 0.f;

    __syncthreads();

    int pS0 = 0, pS1 = 0, pS2 = 0;                       // sibling caches
    int pI0 = 0, pI1 = 0, pI2 = 0, pI3 = 0;              // upstream caches
    int pO0 = 0, pO1 = 0, pO2 = 0, pO3 = 0;              // downstream caches
    const int k0 = rgl*4 + ((w + 1) & 3), k1 = rgl*4 + ((w + 2) & 3), k2 = rgl*4 + ((w + 3) & 3);

    // prologue: input for t=0
    if (l > 0) {
        GWAIT4(pI0, pI1, pI2, pI3, uBase, 1)
        const __fp16* ip = rin + 0 * 1024 + l15 * 64 + 8 * quad;
        xBp0 = *(const f16x8*)ip;
        xBp1 = *(const f16x8*)(ip + 32);
    } else {
        xvp = xs[rgl * 16 + l15];
    }

    for (int t = 0; t < TT; ++t) {
        // sibling wait (need all 4 unit-quarters' h(t-1))
        if (t > 0) { LWAIT(pS0, k0, t) LWAIT(pS1, k1, t) LWAIT(pS2, k2, t) }
        __builtin_amdgcn_s_setprio(1);
        MFMA_SEG4(t)
        __builtin_amdgcn_s_setprio(0);
        // ring-reuse guard for global slot t&7 (consumers done with t-8)
        if (l < 3 && t >= 8) GWAIT4(pO0, pO1, pO2, pO3, dBase, t - 7)
        {
            const bool sv_ = (l == 3) && (t == TT - 1);
            GATE_SEG4(t, sv_)
        }
        // publish: LDS (siblings) + global (inter-layer)
        __hip_atomic_store(&Pf[rgl*4 + w], t + 1, __ATOMIC_RELEASE, __HIP_MEMORY_SCOPE_WORKGROUP);
        if (l < 3) __builtin_amdgcn_fence(__ATOMIC_RELEASE, "agent");
        __hip_atomic_store(&Pg[own], t + 1, __ATOMIC_RELAXED, __HIP_MEMORY_SCOPE_AGENT);
        // prefetch input for t+1 (latency hidden behind next step's work)
        if (t + 1 < TT) {
            if (l > 0) {
                GWAIT4(pI0, pI1, pI2, pI3, uBase, t + 2)
                const __fp16* ip = rin + ((t + 1) & 7) * 1024 + l15 * 64 + 8 * quad;
                xBp0 = *(const f16x8*)ip;
                xBp1 = *(const f16x8*)(ip + 32);
            } else {
                xvp = xs[(t + 1) * 33 + rgl * 16 + l15];
            }
        }
    }

    __syncthreads();

    // ---- epilogue (l==3 blocks), BIT-EXACT R14/R22 arithmetic per rgl ----
    if (l == 3) {
        float* hsv = xs;                       // dead region
        *(f32x4*)(hsv + ((rgl * 4 + w) * 64 + lane) * 4) = hK0;
    }
    __syncthreads();
    if (l == 3 && w < 2) {
        const int h = w;
        const float* hsv = xs;
        f32x4 hk0 = *(const f32x4*)(hsv + ((rgl * 4 + 2 * h)     * 64 + lane) * 4);
        f32x4 hk1 = *(const f32x4*)(hsv + ((rgl * 4 + 2 * h + 1) * 64 + lane) * 4);
        float p = 0.f;
        #pragma unroll
        for (int r = 0; r < 4; ++r) {
            p += hk0[r] * Wd[32 * h + 4 * quad + r];
            p += hk1[r] * Wd[32 * h + 16 + 4 * quad + r];
        }
        p += __shfl_down(p, 32, 64);
        p += __shfl_down(p, 16, 64);
        if (lane < 16) red[rgl * 32 + h * 16 + lane] = p;
    }
    __syncthreads();
    if (l == 3 && w == 0 && lane < 16)
        out[rg * 32 + rgl * 16 + lane] = red[rgl * 32 + lane] + red[rgl * 32 + 16 + lane] + bd[0];
}

// ============================================================================
// Fallback: byte-exact R20 (585us steady, verified) when ws_size insufficient.
// ============================================================================
#define DECLT(j) f16x8 uA##j##_0, uA##j##_1, wA##j##_0, wA##j##_1; f32x4 bias##j;
#define LOADT(j) { \
  const int Tg_ = ((j)>>1)*4 + 2*h + ((j)&1); \
  const float sc_ = (((j)>>1) == 2) ? 1.0f : -1.4426950408889634f; \
  uA##j##_0 = GA(Uw, Tg_, 0, sc_); uA##j##_1 = GA(Uw, Tg_, 1, sc_); \
  bias##j = (f32x4){ bw_[16*Tg_ + 4*quad + 0] * sc_, bw_[16*Tg_ + 4*quad + 1] * sc_, \
                     bw_[16*Tg_ + 4*quad + 2] * sc_, bw_[16*Tg_ + 4*quad + 3] * sc_ }; \
  if (l > 0) { wA##j##_0 = GA(Wsrc, Tg_, 0, sc_); wA##j##_1 = GA(Wsrc, Tg_, 1, sc_); } \
  else { wA##j##_0 = __builtin_bit_cast(f16x8, (f32x4){ \
           Wx0[16*Tg_+4*quad+0] * sc_, Wx0[16*Tg_+4*quad+1] * sc_, \
           Wx0[16*Tg_+4*quad+2] * sc_, Wx0[16*Tg_+4*quad+3] * sc_ }); \
         wA##j##_1 = wA##j##_0; } }

#define MW0(j) acc##j = mfma16(wA##j##_0, xBp0, bias##j);
#define MW1(j) acc##j = mfma16(wA##j##_1, xBp1, acc##j);
#define MX(j)  acc##j = bias##j + __builtin_bit_cast(f32x4, wA##j##_0) * xvp4;
#define MU0(j) acc##j = mfma16(uA##j##_0, hB0, acc##j);
#define MU1(j) acc##j = mfma16(uA##j##_1, hB1, acc##j);

#define MFMA_SEG(t_) { \
  const __fp16* hp_ = hb_l + (((t_)-1)&7)*1152 + l15*72 + 8*quad; \
  f16x8 hB0 = *(const f16x8*)hp_; \
  f16x8 hB1 = *(const f16x8*)(hp_ + 32); \
  if (l > 0) { REP8(MW0) REP8(MW1) } \
  else       { f32x4 xvp4 = {xvp, xvp, xvp, xvp}; REP8(MX) } \
  REP8(MU0) \
  REP8(MU1) }

#define GATES(qp, Ai, Af, Ag, Ao, CST, SAVEK, HK) { \
  f32x4 ei_, ef_, eo_; \
  _Pragma("unroll") for (int r_ = 0; r_ < 4; ++r_) { \
    ei_[r_] = __builtin_amdgcn_exp2f(Ai[r_]); \
    ef_[r_] = __builtin_amdgcn_exp2f(Af[r_]); \
    eo_[r_] = __builtin_amdgcn_exp2f(Ao[r_]); \
  } \
  f32x4 si_, sf_, so_; \
  _Pragma("unroll") for (int r_ = 0; r_ < 4; ++r_) { \
    si_[r_] = __builtin_amdgcn_rcpf(1.0f + ei_[r_]); \
    sf_[r_] = __builtin_amdgcn_rcpf(1.0f + ef_[r_]); \
    so_[r_] = __builtin_amdgcn_rcpf(1.0f + eo_[r_]); \
  } \
  const f32x4 z4_ = {0.f, 0.f, 0.f, 0.f}; \
  f32x4 rg_ = __builtin_elementwise_max(Ag, z4_); \
  f32x4 cv_ = sf_ * CST + si_ * rg_; \
  CST = cv_; \
  f32x4 hv_ = so_ * __builtin_elementwise_max(cv_, z4_); \
  u32x2 pv_ = { pkf16(hv_[0], hv_[1]), pkf16(hv_[2], hv_[3]) }; \
  *(u32x2*)(hw_ + 16*(qp)) = pv_; \
  if (SAVEK) HK = hv_; }

#define GATE_SEG(tg_, SV_) { \
  __fp16* hw_ = hb_l + ((tg_)&7)*1152 + l15*72 + 32*h + 4*quad; \
  GATES(0, acc0, acc2, acc4, acc6, cst0, SV_, hK0) \
  GATES(1, acc1, acc3, acc5, acc7, cst1, SV_, hK1) }

#define WAITGE(cache, idx, need) \
  while ((cache) < (need)) \
    (cache) = __hip_atomic_load(&Pf[idx], __ATOMIC_ACQUIRE, __HIP_MEMORY_SCOPE_WORKGROUP);

__global__ __launch_bounds__(512)
__attribute__((amdgpu_waves_per_eu(2, 2)))
void lstm_fb(
    const float* __restrict__ x,
    const float* __restrict__ Wx0, const float* __restrict__ U0, const float* __restrict__ b0,
    const float* __restrict__ Wx1, const float* __restrict__ U1, const float* __restrict__ b1,
    const float* __restrict__ Wx2, const float* __restrict__ U2, const float* __restrict__ b2,
    const float* __restrict__ Wx3, const float* __restrict__ U3, const float* __restrict__ b3,
    const float* __restrict__ Wd,  const float* __restrict__ bd,
    float* __restrict__ out)
{
    extern __shared__ uint32_t smem[];
    __fp16* hb16 = (__fp16*)smem;
    float*  xs   = (float*)(smem + 18432);
    float*  red  = (float*)(smem + 27136);
    int*    Pf   = (int*)(smem + 27168);

    const int tid  = threadIdx.x;
    const int lane = tid & 63;
    const int l15  = lane & 15;
    const int quad = lane >> 4;
    const int wv   = tid >> 6;
    const int l    = wv >> 1;
    const int h    = wv & 1;
    const int b0i  = blockIdx.x * 16;

    for (int i = tid; i < 27176; i += 512) smem[i] = 0;
    __syncthreads();
    for (int i = tid; i < 16 * TT; i += 512) {
        int row = i >> 9, t_ = i & (TT - 1);
        xs[t_ * 17 + row] = x[(b0i + row) * TT + t_];
    }

    const float* Uw   = (l == 0) ? U0 : (l == 1) ? U1 : (l == 2) ? U2 : U3;
    const float* bw_  = (l == 0) ? b0 : (l == 1) ? b1 : (l == 2) ? b2 : b3;
    const float* Wsrc = (l == 1) ? Wx1 : (l == 2) ? Wx2 : (l == 3) ? Wx3 : U0;

    REP8(DECLT)
    REP8(LOADT)

    f32x4 acc0, acc1, acc2, acc3, acc4, acc5, acc6, acc7;
    f32x4 cst0 = {0,0,0,0}, cst1 = {0,0,0,0};
    f32x4 hK0  = {0,0,0,0}, hK1  = {0,0,0,0};

    __fp16* hb_l  = hb16 + l * 9216;
    const __fp16* hb_in = hb16 + (l > 0 ? (l - 1) * 9216 : 0);

    f16x8 xBp0 = {}, xBp1 = {};
    float xvp = 0.f;

    __syncthreads();

    if (l == 0) xvp = xs[l15];

    int pA0 = 0, pA1 = 0, pP = 0, pC0 = 0, pC1 = 0;

    for (int t = 0; t < TT; ++t) {
        if (l > 0) {
            WAITGE(pA0, 2*l - 2, t + 1)
            WAITGE(pA1, 2*l - 1, t + 1)
            const __fp16* xp_ = hb_in + (t & 7) * 1152 + l15 * 72 + 8 * quad;
            xBp0 = *(const f16x8*)xp_;
            xBp1 = *(const f16x8*)(xp_ + 32);
        }
        if (t > 0) WAITGE(pP, 2*l + 1 - h, t)
        if (l < 3 && t >= 8) {
            WAITGE(pC0, 2*l + 2, t - 7)
            WAITGE(pC1, 2*l + 3, t - 7)
        }
        __builtin_amdgcn_s_setprio(1);
        MFMA_SEG(t)
        __builtin_amdgcn_s_setprio(0);
        {
            const bool sv_ = (l == 3) && (t == TT - 1);
            GATE_SEG(t, sv_)
        }
        __hip_atomic_store(&Pf[2*l + h], t + 1, __ATOMIC_RELEASE, __HIP_MEMORY_SCOPE_WORKGROUP);
        if (l == 0 && t + 1 < TT) xvp = xs[(t + 1) * 17 + l15];
    }

    __syncthreads();

    if (l == 3) {
        float p = 0.f;
        #pragma unroll
        for (int r = 0; r < 4; ++r) {
            p += hK0[r] * Wd[32 * h + 4 * quad + r];
            p += hK1[r] * Wd[32 * h + 16 + 4 * quad + r];
        }
        p += __shfl_down(p, 32, 64);
        p += __shfl_down(p, 16, 64);
        if (lane < 16) red[h * 16 + lane] = p;
    }
    __syncthreads();
    if (wv == 6 && lane < 16) out[b0i + lane] = red[lane] + red[16 + lane] + bd[0];
}

extern "C" void kernel_launch(void* const* d_in, const int* in_sizes, int n_in,
                              void* d_out, int out_size, void* d_ws, size_t ws_size,
                              hipStream_t stream) {
    const float* x   = (const float*)d_in[0];
    const float* Wx0 = (const float*)d_in[1];
    const float* U0  = (const float*)d_in[2];
    const float* b0  = (const float*)d_in[3];
    const float* Wx1 = (const float*)d_in[4];
    const float* U1  = (const float*)d_in[5];
    const float* b1  = (const float*)d_in[6];
    const float* Wx2 = (const float*)d_in[7];
    const float* U2  = (const float*)d_in[8];
    const float* b2  = (const float*)d_in[9];
    const float* Wx3 = (const float*)d_in[10];
    const float* U3  = (const float*)d_in[11];
    const float* b3  = (const float*)d_in[12];
    const float* Wd  = (const float*)d_in[13];
    const float* bd  = (const float*)d_in[14];
    float* out = (float*)d_out;

    const size_t RING_BYTES = 3145728;   // 3 layers x 32 rg x 2 rgl x 8 slots x 2KB
    const size_t FLAG_BYTES = 4096;      // 1024 int counters

    if (d_ws != nullptr && ws_size >= RING_BYTES + FLAG_BYTES) {
        (void)hipMemsetAsync((char*)d_ws + RING_BYTES, 0, FLAG_BYTES, stream);
        static const int kLdsLP = 26184 * 4;   // 104736 B
        (void)hipFuncSetAttribute((const void*)lstm_lp,
                                  hipFuncAttributeMaxDynamicSharedMemorySize, kLdsLP);
        hipLaunchKernelGGL(lstm_lp, dim3(128), dim3(512), kLdsLP, stream,
                           x, Wx0, U0, b0, Wx1, U1, b1, Wx2, U2, b2, Wx3, U3, b3,
                           Wd, bd, out, d_ws);
    } else {
        static const int kLdsFB = 27176 * 4;   // 108704 B
        (void)hipFuncSetAttribute((const void*)lstm_fb,
                                  hipFuncAttributeMaxDynamicSharedMemorySize, kLdsFB);
        hipLaunchKernelGGL(lstm_fb, dim3(64), dim3(512), kLdsFB, stream,
                           x, Wx0, U0, b0, Wx1, U1, b1, Wx2, U2, b2, Wx3, U3, b3,
                           Wd, bd, out);
    }
}

// Round 16
// 638.541 us; speedup vs baseline: 13.6658x; 13.6658x over previous
//
#include <hip/hip_runtime.h>
#include <stdint.h>

#define TT 512

typedef __fp16   f16x8  __attribute__((ext_vector_type(8)));
typedef float    f32x4  __attribute__((ext_vector_type(4)));
typedef __fp16   fp16x2 __attribute__((ext_vector_type(2)));
typedef uint32_t u32x2  __attribute__((ext_vector_type(2)));

__device__ __forceinline__ f32x4 mfma16(f16x8 a, f16x8 b, f32x4 c) {
    return __builtin_amdgcn_mfma_f32_16x16x32_f16(a, b, c, 0, 0, 0);
}
__device__ __forceinline__ uint32_t pkf16(float a, float b) {
    fp16x2 h = __builtin_amdgcn_cvt_pkrtz(a, b);
    return __builtin_bit_cast(uint32_t, h);
}

#define REP8(M) M(0)M(1)M(2)M(3)M(4)M(5)M(6)M(7)

// A-operand gather with per-column scale SC (weights transposed, z^T form):
// A[m=16T+l15][k=32F+8q+j] = SRC[k][16T+l15] * SC
#define GA(SRC, T, F, SC) (f16x8){ \
  (__fp16)((SRC)[(32*(F)+8*quad+0)*256 + 16*(T)+l15] * (SC)), \
  (__fp16)((SRC)[(32*(F)+8*quad+1)*256 + 16*(T)+l15] * (SC)), \
  (__fp16)((SRC)[(32*(F)+8*quad+2)*256 + 16*(T)+l15] * (SC)), \
  (__fp16)((SRC)[(32*(F)+8*quad+3)*256 + 16*(T)+l15] * (SC)), \
  (__fp16)((SRC)[(32*(F)+8*quad+4)*256 + 16*(T)+l15] * (SC)), \
  (__fp16)((SRC)[(32*(F)+8*quad+5)*256 + 16*(T)+l15] * (SC)), \
  (__fp16)((SRC)[(32*(F)+8*quad+6)*256 + 16*(T)+l15] * (SC)), \
  (__fp16)((SRC)[(32*(F)+8*quad+7)*256 + 16*(T)+l15] * (SC)) }

// Wave (l,h) owns zcols {64g + 32h + 16q' .. +15}: local j = 2g+q' -> tile Tg.
// Gate index = j>>1 (0:i 1:f 2:g 3:o). i/f/o columns+bias pre-scaled by -log2e
// at load time (R19 fold).
#define DECLT(j) f16x8 uA##j##_0, uA##j##_1, wA##j##_0, wA##j##_1; f32x4 bias##j;
#define LOADT(j) { \
  const int Tg_ = ((j)>>1)*4 + 2*h + ((j)&1); \
  const float sc_ = (((j)>>1) == 2) ? 1.0f : -1.4426950408889634f; \
  uA##j##_0 = GA(Uw, Tg_, 0, sc_); uA##j##_1 = GA(Uw, Tg_, 1, sc_); \
  bias##j = (f32x4){ bw_[16*Tg_ + 4*quad + 0] * sc_, bw_[16*Tg_ + 4*quad + 1] * sc_, \
                     bw_[16*Tg_ + 4*quad + 2] * sc_, bw_[16*Tg_ + 4*quad + 3] * sc_ }; \
  if (l > 0) { wA##j##_0 = GA(Wsrc, Tg_, 0, sc_); wA##j##_1 = GA(Wsrc, Tg_, 1, sc_); } \
  else { wA##j##_0 = __builtin_bit_cast(f16x8, (f32x4){ \
           Wx0[16*Tg_+4*quad+0] * sc_, Wx0[16*Tg_+4*quad+1] * sc_, \
           Wx0[16*Tg_+4*quad+2] * sc_, Wx0[16*Tg_+4*quad+3] * sc_ }); \
         wA##j##_1 = wA##j##_0; } }

// MFMA segment: hB ds_read hoisted at top (latency hides under the 16
// partner-independent W-MFMAs that follow) -- R14's proven order, untouched.
#define MW0(j) acc##j = mfma16(wA##j##_0, xBp0, bias##j);
#define MW1(j) acc##j = mfma16(wA##j##_1, xBp1, acc##j);
#define MX(j)  acc##j = bias##j + __builtin_bit_cast(f32x4, wA##j##_0) * xvp4;
#define MU0(j) acc##j = mfma16(uA##j##_0, hB0, acc##j);
#define MU1(j) acc##j = mfma16(uA##j##_1, hB1, acc##j);

#define MFMA_SEG(t_) { \
  const __fp16* hp_ = hb_l + (((t_)-1)&7)*1152 + l15*72 + 8*quad; \
  f16x8 hB0 = *(const f16x8*)hp_; \
  f16x8 hB1 = *(const f16x8*)(hp_ + 32); \
  if (l > 0) { REP8(MW0) REP8(MW1) } \
  else       { f32x4 xvp4 = {xvp, xvp, xvp, xvp}; REP8(MX) } \
  REP8(MU0) \
  REP8(MU1) }

// Gates: z' for i/f/o pre-scaled -> exp2 direct; g unscaled (relu only).
#define GATES(qp, Ai, Af, Ag, Ao, CST, SAVEK, HK) { \
  f32x4 ei_, ef_, eo_; \
  _Pragma("unroll") for (int r_ = 0; r_ < 4; ++r_) { \
    ei_[r_] = __builtin_amdgcn_exp2f(Ai[r_]); \
    ef_[r_] = __builtin_amdgcn_exp2f(Af[r_]); \
    eo_[r_] = __builtin_amdgcn_exp2f(Ao[r_]); \
  } \
  f32x4 si_, sf_, so_; \
  _Pragma("unroll") for (int r_ = 0; r_ < 4; ++r_) { \
    si_[r_] = __builtin_amdgcn_rcpf(1.0f + ei_[r_]); \
    sf_[r_] = __builtin_amdgcn_rcpf(1.0f + ef_[r_]); \
    so_[r_] = __builtin_amdgcn_rcpf(1.0f + eo_[r_]); \
  } \
  const f32x4 z4_ = {0.f, 0.f, 0.f, 0.f}; \
  f32x4 rg_ = __builtin_elementwise_max(Ag, z4_); \
  f32x4 cv_ = sf_ * CST + si_ * rg_; \
  CST = cv_; \
  f32x4 hv_ = so_ * __builtin_elementwise_max(cv_, z4_); \
  u32x2 pv_ = { pkf16(hv_[0], hv_[1]), pkf16(hv_[2], hv_[3]) }; \
  *(u32x2*)(hw_ + 16*(qp)) = pv_; \
  if (SAVEK) HK = hv_; }

#define GATE_SEG(tg_, SV_) { \
  __fp16* hw_ = hb_l + ((tg_)&7)*1152 + l15*72 + 32*h + 4*quad; \
  GATES(0, acc0, acc2, acc4, acc6, cst0, SV_, hK0) \
  GATES(1, acc1, acc3, acc5, acc7, cst1, SV_, hK1) }

// Spin-wait on a progress counter (workgroup-scope LDS atomic, cached locally).
#define WAITGE(cache, idx, need) \
  while ((cache) < (need)) \
    (cache) = __hip_atomic_load(&Pf[idx], __ATOMIC_ACQUIRE, __HIP_MEMORY_SCOPE_WORKGROUP);

// 64 blocks x 512 threads; block = 16 batch rows; 8 waves = 4 layers x 2 unit-halves.
// R26 = BYTE-EXACT RESTORE of R20 (best verified: 585us steady / 641 headline).
// Session ledger: async flag decoupling +7% (R14), setprio +2.5% (R20), exp2
// fold neutral (R19), all schedule reorders negative (R16-R18), s_sleep -3%
// (R24), 4-wave TLP register-infeasible (R21-R23: 16 waves/CU caps unified
// VGPR+AGPR at ~128/wave vs ~200-reg working set), 1-wave/SIMD 2x worse (R15),
// layer-parallel global ring 15x worse (R25: cross-XCD fence+poll on the
// 512-step chain, 237MB HBM traffic). Remaining gap to the 265us matrix floor
// is the per-step recurrence chain -- no tested lever moves it below ~585.
__global__ __launch_bounds__(512)
__attribute__((amdgpu_waves_per_eu(2, 2)))
void lstm_phase(
    const float* __restrict__ x,
    const float* __restrict__ Wx0, const float* __restrict__ U0, const float* __restrict__ b0,
    const float* __restrict__ Wx1, const float* __restrict__ U1, const float* __restrict__ b1,
    const float* __restrict__ Wx2, const float* __restrict__ U2, const float* __restrict__ b2,
    const float* __restrict__ Wx3, const float* __restrict__ U3, const float* __restrict__ b3,
    const float* __restrict__ Wd,  const float* __restrict__ bd,
    float* __restrict__ out)
{
    // dwords: hbuf f16 [0,18432) | x_s f32 [18432,27136) | red [27136,27168) | P [27168,27176)
    extern __shared__ uint32_t smem[];
    __fp16* hb16 = (__fp16*)smem;              // [l][slot8][row 16][unit 64 pad 72]
    float*  xs   = (float*)(smem + 18432);     // [t][17]
    float*  red  = (float*)(smem + 27136);     // [2][16] epilogue partials
    int*    Pf   = (int*)(smem + 27168);       // [8] per-wave progress counters

    const int tid  = threadIdx.x;
    const int lane = tid & 63;
    const int l15  = lane & 15;
    const int quad = lane >> 4;
    const int wv   = tid >> 6;
    const int l    = wv >> 1;                  // layer
    const int h    = wv & 1;                   // unit-half
    const int b0i  = blockIdx.x * 16;

    // ---- staging: zero hbuf + flags, stage x ----
    for (int i = tid; i < 27176; i += 512) smem[i] = 0;
    __syncthreads();
    for (int i = tid; i < 16 * TT; i += 512) {
        int row = i >> 9, t_ = i & (TT - 1);
        xs[t_ * 17 + row] = x[(b0i + row) * TT + t_];
    }

    const float* Uw   = (l == 0) ? U0 : (l == 1) ? U1 : (l == 2) ? U2 : U3;
    const float* bw_  = (l == 0) ? b0 : (l == 1) ? b1 : (l == 2) ? b2 : b3;
    const float* Wsrc = (l == 1) ? Wx1 : (l == 2) ? Wx2 : (l == 3) ? Wx3 : U0;

    REP8(DECLT)
    REP8(LOADT)

    f32x4 acc0, acc1, acc2, acc3, acc4, acc5, acc6, acc7;
    f32x4 cst0 = {0,0,0,0}, cst1 = {0,0,0,0};
    f32x4 hK0  = {0,0,0,0}, hK1  = {0,0,0,0};

    __fp16* hb_l  = hb16 + l * 9216;           // own buffer (8 slots x 1152 f16)
    const __fp16* hb_in = hb16 + (l > 0 ? (l - 1) * 9216 : 0);

    f16x8 xBp0 = {}, xBp1 = {};
    float xvp = 0.f;

    __syncthreads();

    if (l == 0) xvp = xs[l15];                 // layer-0 operand for t=0

    int pA0 = 0, pA1 = 0, pP = 0, pC0 = 0, pC1 = 0;   // cached counter values

    for (int t = 0; t < TT; ++t) {
        if (l > 0) {
            WAITGE(pA0, 2*l - 2, t + 1)
            WAITGE(pA1, 2*l - 1, t + 1)
            const __fp16* xp_ = hb_in + (t & 7) * 1152 + l15 * 72 + 8 * quad;
            xBp0 = *(const f16x8*)xp_;
            xBp1 = *(const f16x8*)(xp_ + 32);
        }
        if (t > 0) WAITGE(pP, 2*l + 1 - h, t)
        if (l < 3 && t >= 8) {                 // ring-reuse guard (slot t&7 = h(t-8))
            WAITGE(pC0, 2*l + 2, t - 7)
            WAITGE(pC1, 2*l + 3, t - 7)
        }
        __builtin_amdgcn_s_setprio(1);
        MFMA_SEG(t)
        __builtin_amdgcn_s_setprio(0);
        {
            const bool sv_ = (l == 3) && (t == TT - 1);
            GATE_SEG(t, sv_)
        }
        __hip_atomic_store(&Pf[2*l + h], t + 1, __ATOMIC_RELEASE, __HIP_MEMORY_SCOPE_WORKGROUP);
        if (l == 0 && t + 1 < TT) xvp = xs[(t + 1) * 17 + l15];
    }

    __syncthreads();

    // dense epilogue: waves (3,h); lane holds h[511] f32 for units 32h+16q'+4quad+r, row l15
    if (l == 3) {
        float p = 0.f;
        #pragma unroll
        for (int r = 0; r < 4; ++r) {
            p += hK0[r] * Wd[32 * h + 4 * quad + r];
            p += hK1[r] * Wd[32 * h + 16 + 4 * quad + r];
        }
        p += __shfl_down(p, 32, 64);
        p += __shfl_down(p, 16, 64);
        if (lane < 16) red[h * 16 + lane] = p;
    }
    __syncthreads();
    if (wv == 6 && lane < 16) out[b0i + lane] = red[lane] + red[16 + lane] + bd[0];
}

extern "C" void kernel_launch(void* const* d_in, const int* in_sizes, int n_in,
                              void* d_out, int out_size, void* d_ws, size_t ws_size,
                              hipStream_t stream) {
    const float* x   = (const float*)d_in[0];
    const float* Wx0 = (const float*)d_in[1];
    const float* U0  = (const float*)d_in[2];
    const float* b0  = (const float*)d_in[3];
    const float* Wx1 = (const float*)d_in[4];
    const float* U1  = (const float*)d_in[5];
    const float* b1  = (const float*)d_in[6];
    const float* Wx2 = (const float*)d_in[7];
    const float* U2  = (const float*)d_in[8];
    const float* b2  = (const float*)d_in[9];
    const float* Wx3 = (const float*)d_in[10];
    const float* U3  = (const float*)d_in[11];
    const float* b3  = (const float*)d_in[12];
    const float* Wd  = (const float*)d_in[13];
    const float* bd  = (const float*)d_in[14];
    float* out = (float*)d_out;

    static const int kLds = 27176 * 4;   // 108704 B dynamic LDS
    (void)hipFuncSetAttribute((const void*)lstm_phase,
                              hipFuncAttributeMaxDynamicSharedMemorySize, kLds);
    hipLaunchKernelGGL(lstm_phase, dim3(64), dim3(512), kLds, stream,
                       x, Wx0, U0, b0, Wx1, U1, b1, Wx2, U2, b2, Wx3, U3, b3,
                       Wd, bd, out);
}